// Round 1
// baseline (497.184 us; speedup 1.0000x reference)
//
#include <hip/hip_runtime.h>
#include <math.h>

// SphericalSpectralTimeConv: L_in=L_out=128 (NT=128 thetas, NPHI=255 phis),
// Lf=64 (NM=64 m>=0, NJ=127 signed m), Cin=Cout=64, T=256.
//
// ws layout (float offsets). G overlaps FMW/TC/FLM/RT which are dead by the
// time k_g runs. Total = 3,678,720 floats = 14.7 MB.
#define PI_D 3.14159265358979323846
static const size_t OFF_P   = 0;         // float  [64m][64l][128t]
static const size_t OFF_W   = 524288;    // float  [128]
static const size_t OFF_TW  = 524416;    // float2 [255]
static const size_t OFF_FMW = 524928;    // float2 [64m][128t][64c]
static const size_t OFF_TC  = 1573504;   // float2 [64l][127j]
static const size_t OFF_FLM = 1589760;   // float2 [64l][64m][64c]
static const size_t OFF_RT  = 2114048;   // float2 [64l][64o][64i]
static const size_t OFF_FO  = 2638336;   // float2 [64l][127j][64o]
static const size_t OFF_G   = 524928;    // float2 [128t][127j][64o] (overlay)
static const size_t WS_FLOATS = 3678720;

// K0: quadrature weights (double, incremental rotations) + twiddle table.
__global__ __launch_bounds__(256) void k_tables(float* __restrict__ w, float2* __restrict__ tw) {
  int tid = threadIdx.x;
  if (tid < 255) {
    double a = 2.0 * PI_D * tid / 255.0;
    tw[tid] = make_float2((float)cos(a), (float)sin(a));
  }
  if (tid < 128) {
    int t = tid;
    // u = e^{-i pi m/255}, v1 = e^{-2pi i m t/255}, v2 = e^{+2pi i m (t+1)/255}, start m=-127
    double ur = cos(127.0 * PI_D / 255.0), ui = sin(127.0 * PI_D / 255.0);
    double dur = cos(PI_D / 255.0), dui = -sin(PI_D / 255.0);
    double a1 = 2.0 * PI_D * 127.0 * t / 255.0;
    double v1r = cos(a1), v1i = sin(a1);
    double d1r = cos(2.0 * PI_D * t / 255.0), d1i = -sin(2.0 * PI_D * t / 255.0);
    double a2 = -2.0 * PI_D * 127.0 * (t + 1) / 255.0;
    double v2r = cos(a2), v2i = sin(a2);
    double d2r = cos(2.0 * PI_D * (t + 1) / 255.0), d2i = sin(2.0 * PI_D * (t + 1) / 255.0);
    double q = 0.0;
    for (int m = -127; m <= 127; ++m) {
      double br = 0.0, bi = 0.0; bool active = true;
      if (m == 1) bi = PI_D / 2.0;
      else if (m == -1) bi = -PI_D / 2.0;
      else if ((m & 1) == 0) br = 2.0 / (1.0 - (double)m * (double)m);
      else active = false;
      if (active) {
        double wr = br * ur - bi * ui;
        double wi = br * ui + bi * ur;
        double fr = v1r, fi = v1i;
        if (t < 127) { fr += v2r; fi += v2i; }
        q += wr * fr - wi * fi;
      }
      double nr;
      nr = ur * dur - ui * dui;  ui = ur * dui + ui * dur;  ur = nr;
      nr = v1r * d1r - v1i * d1i; v1i = v1r * d1i + v1i * d1r; v1r = nr;
      nr = v2r * d2r - v2i * d2i; v2i = v2r * d2i + v2i * d2r; v2r = nr;
    }
    w[t] = (float)(q * 2.0 * PI_D / (255.0 * 255.0));
  }
}

// K1: associated Legendre table P[m][l][t], l,m < 64, t < 128 (double recurrences).
__global__ __launch_bounds__(128) void k_legendre(float* __restrict__ P) {
  int m = blockIdx.x, t = threadIdx.x;
  double th = PI_D * (2 * t + 1) / 255.0;
  double ct = cos(th), st = sin(th);
  double pmm = 0.28209479177387814;  // 1/sqrt(4 pi)
  for (int k = 1; k <= m; ++k) pmm *= -sqrt((2.0 * k + 1.0) / (2.0 * k)) * st;
  float* Pm = P + ((size_t)m * 64) * 128;
  Pm[(size_t)m * 128 + t] = (float)pmm;
  if (m + 1 < 64) {
    double p0 = pmm, p1 = sqrt(2.0 * m + 3.0) * ct * pmm;
    Pm[(size_t)(m + 1) * 128 + t] = (float)p1;
    for (int l = m + 2; l < 64; ++l) {
      double ll = (double)l * l, mm = (double)m * m;
      double a = sqrt((4.0 * ll - 1.0) / (ll - mm));
      double b = sqrt((2.0 * l + 1.0) * ((double)(l - 1) * (l - 1) - mm) / ((2.0 * l - 3.0) * (ll - mm)));
      double pl = a * ct * p1 - b * p0;
      Pm[(size_t)l * 128 + t] = (float)pl;
      p0 = p1; p1 = pl;
    }
  }
}

// K2: forward DFT over phi, Fmw[m][t][c] = w[t] * sum_p x[t][p][c] e^{-2pi i m p/255}.
// grid (t=128, ch=2), block 256 = (c32 lanes x 8 m-groups), 8 m per thread.
__global__ __launch_bounds__(256) void k_fwd_dft(const float* __restrict__ x, const float* __restrict__ w,
                                                 const float2* __restrict__ tw, float2* __restrict__ Fmw) {
  int t = blockIdx.x, ch = blockIdx.y;
  __shared__ float xs[32 * 255];
  __shared__ float2 tws[255];
  int tid = threadIdx.x;
  if (tid < 255) tws[tid] = tw[tid];
  for (int idx = tid; idx < 32 * 255; idx += 256) {
    int c = idx & 31, p = idx >> 5;
    xs[c * 255 + p] = x[((size_t)t * 255 + p) * 64 + ch * 32 + c];
  }
  __syncthreads();
  int c = tid & 31, mg = tid >> 5;
  int mbase = mg << 3;
  float accr[8], acci[8];
  int k[8];
#pragma unroll
  for (int j = 0; j < 8; ++j) { accr[j] = 0.f; acci[j] = 0.f; k[j] = 0; }
  const float* xrow = xs + c * 255;
  for (int p = 0; p < 255; ++p) {
    float xv = xrow[p];
#pragma unroll
    for (int j = 0; j < 8; ++j) {
      float2 tt = tws[k[j]];
      accr[j] += xv * tt.x;
      acci[j] -= xv * tt.y;
      k[j] += mbase + j;
      if (k[j] >= 255) k[j] -= 255;
    }
  }
  float wt = w[t];
#pragma unroll
  for (int j = 0; j < 8; ++j) {
    int m = mbase + j;
    Fmw[((size_t)m * 128 + t) * 64 + ch * 32 + c] = make_float2(wt * accr[j], wt * acci[j]);
  }
}

// K3: t_c[l][j] = sum_t t_emb[t] * (A_real + i A_imag)[l][j][t]. One block per (l,j).
__global__ __launch_bounds__(256) void k_tc(const float* __restrict__ te, const float* __restrict__ Ar,
                                            const float* __restrict__ Ai, float2* __restrict__ tc) {
  int bid = blockIdx.x;  // l*127 + j
  int tid = threadIdx.x;
  float e = te[tid];
  float vr = Ar[(size_t)bid * 256 + tid] * e;
  float vi = Ai[(size_t)bid * 256 + tid] * e;
  for (int off = 32; off; off >>= 1) {
    vr += __shfl_down(vr, off);
    vi += __shfl_down(vi, off);
  }
  __shared__ float2 red[4];
  if ((tid & 63) == 0) red[tid >> 6] = make_float2(vr, vi);
  __syncthreads();
  if (tid == 0) {
    float2 s = red[0];
    for (int q = 1; q < 4; ++q) { s.x += red[q].x; s.y += red[q].y; }
    tc[bid] = s;
  }
}

// K4: Rt[l][o][i] = sum_j t_c[l][j] * (R_real + i R_imag)[l][j][o][i].  HBM-bound (266 MB).
__global__ __launch_bounds__(256) void k_rt(const float* __restrict__ Rr, const float* __restrict__ Ri,
                                            const float2* __restrict__ tc, float2* __restrict__ Rt) {
  int l = blockIdx.x, og = blockIdx.y;
  int i = threadIdx.x & 63, ol = threadIdx.x >> 6;
  int o = og * 4 + ol;
  const float* rr = Rr + ((size_t)l * 127) * 4096 + o * 64 + i;
  const float* ri = Ri + ((size_t)l * 127) * 4096 + o * 64 + i;
  const float2* tcl = tc + l * 127;
  float ar = 0.f, ai2 = 0.f;
#pragma unroll 4
  for (int j = 0; j < 127; ++j) {
    float2 w2 = tcl[j];
    float a = rr[(size_t)j * 4096], b = ri[(size_t)j * 4096];
    ar  += w2.x * a - w2.y * b;
    ai2 += w2.x * b + w2.y * a;
  }
  Rt[((size_t)l * 64 + o) * 64 + i] = make_float2(ar, ai2);
}

// K5: flm[l][m][c] = sum_t P[m][l][t] * Fmw[m][t][c].  grid (m=64, lq=4), block (c64 x lg4).
__global__ __launch_bounds__(256) void k_flm(const float* __restrict__ P, const float2* __restrict__ Fmw,
                                             float2* __restrict__ flm) {
  int m = blockIdx.x, lq = blockIdx.y;
  int c = threadIdx.x & 63, lg = threadIdx.x >> 6;
  int loff = lq * 4 + lg;  // 0..15
  __shared__ float2 Fs[64][64];  // 32 KB, one t-half at a time
  float2 acc[4];
#pragma unroll
  for (int s = 0; s < 4; ++s) acc[s] = make_float2(0.f, 0.f);
  for (int th = 0; th < 2; ++th) {
    __syncthreads();
    for (int idx = threadIdx.x; idx < 4096; idx += 256) {
      int tt = idx >> 6, cc = idx & 63;
      Fs[tt][cc] = Fmw[((size_t)m * 128 + th * 64 + tt) * 64 + cc];
    }
    __syncthreads();
#pragma unroll
    for (int s = 0; s < 4; ++s) {
      int l = m + loff + 16 * s;
      if (l < 64) {
        const float* Pl = P + ((size_t)m * 64 + l) * 128 + th * 64;
        float2 a = acc[s];
#pragma unroll 8
        for (int tt = 0; tt < 64; ++tt) {
          float pv = Pl[tt];
          float2 f = Fs[tt][c];
          a.x += pv * f.x;
          a.y += pv * f.y;
        }
        acc[s] = a;
      }
    }
  }
#pragma unroll
  for (int s = 0; s < 4; ++s) {
    int l = m + loff + 16 * s;
    if (l < 64) flm[((size_t)l * 64 + m) * 64 + c] = acc[s];
  }
}

// K6: flm_out[l][j][o] = sum_i flm_signed[l][j][i] * Rt[l][o][i] (complex*complex).
// flm_signed[l][-m] = (-1)^m conj(flm[l][m]); zero for l < |m|.
__global__ __launch_bounds__(256) void k_flmout(const float2* __restrict__ flm, const float2* __restrict__ Rt,
                                                float2* __restrict__ fo) {
  int l = blockIdx.x, jg = blockIdx.y;
  int o = threadIdx.x & 63, js = threadIdx.x >> 6;
  __shared__ float2 Rts[64][65];
  __shared__ float2 Fjs[16][64];
  for (int idx = threadIdx.x; idx < 4096; idx += 256) {
    int oo = idx >> 6, ii = idx & 63;
    Rts[oo][ii] = Rt[((size_t)l * 64 + oo) * 64 + ii];
  }
  for (int idx = threadIdx.x; idx < 1024; idx += 256) {
    int jl = idx >> 6, ii = idx & 63;
    int j = jg * 16 + jl;
    float2 v = make_float2(0.f, 0.f);
    if (j < 127) {
      int mm = j - 63, am = mm < 0 ? -mm : mm;
      if (l >= am) {
        float2 f = flm[((size_t)l * 64 + am) * 64 + ii];
        if (mm < 0) { float s = (am & 1) ? -1.f : 1.f; v = make_float2(s * f.x, -s * f.y); }
        else v = f;
      }
    }
    Fjs[jl][ii] = v;
  }
  __syncthreads();
  float2 acc[4];
#pragma unroll
  for (int q = 0; q < 4; ++q) acc[q] = make_float2(0.f, 0.f);
  for (int i = 0; i < 64; ++i) {
    float2 r = Rts[o][i];
#pragma unroll
    for (int q = 0; q < 4; ++q) {
      float2 f = Fjs[js * 4 + q][i];
      acc[q].x += f.x * r.x - f.y * r.y;
      acc[q].y += f.x * r.y + f.y * r.x;
    }
  }
#pragma unroll
  for (int q = 0; q < 4; ++q) {
    int j = jg * 16 + js * 4 + q;
    if (j < 127) fo[((size_t)l * 127 + j) * 64 + o] = acc[q];
  }
}

// K7: G[t][j][o] = sgn * sum_{l>=|m|} P[|m|][l][t] * flm_out[l][j][o].
// grid (j=127, tg=2), block (o64 x ts4), 16 t per thread.
__global__ __launch_bounds__(256) void k_g(const float* __restrict__ P, const float2* __restrict__ fo,
                                           float2* __restrict__ G) {
  int j = blockIdx.x, tg = blockIdx.y;
  int mm = j - 63, am = mm < 0 ? -mm : mm;
  float sgn = (mm < 0 && (am & 1)) ? -1.f : 1.f;
  int o = threadIdx.x & 63, ts = threadIdx.x >> 6;
  __shared__ float Ps[64][64];
  __shared__ float2 Fos[64][64];
  for (int idx = threadIdx.x; idx < 4096; idx += 256) {
    int ll = idx >> 6, tt = idx & 63;
    Ps[ll][tt] = P[((size_t)am * 64 + ll) * 128 + tg * 64 + tt];
  }
  for (int idx = threadIdx.x; idx < 4096; idx += 256) {
    int ll = idx >> 6, oo = idx & 63;
    float2 v = fo[((size_t)ll * 127 + j) * 64 + oo];
    Fos[ll][oo] = make_float2(sgn * v.x, sgn * v.y);
  }
  __syncthreads();
  float ar[16], ai2[16];
#pragma unroll
  for (int r = 0; r < 16; ++r) { ar[r] = 0.f; ai2[r] = 0.f; }
  for (int l = am; l < 64; ++l) {
    float2 f = Fos[l][o];
#pragma unroll
    for (int q = 0; q < 4; ++q) {
      float4 pv = *reinterpret_cast<const float4*>(&Ps[l][ts * 16 + q * 4]);
      ar[q * 4 + 0] += pv.x * f.x;  ai2[q * 4 + 0] += pv.x * f.y;
      ar[q * 4 + 1] += pv.y * f.x;  ai2[q * 4 + 1] += pv.y * f.y;
      ar[q * 4 + 2] += pv.z * f.x;  ai2[q * 4 + 2] += pv.z * f.y;
      ar[q * 4 + 3] += pv.w * f.x;  ai2[q * 4 + 3] += pv.w * f.y;
    }
  }
#pragma unroll
  for (int r = 0; r < 16; ++r) {
    int t = tg * 64 + ts * 16 + r;
    G[((size_t)t * 127 + j) * 64 + o] = make_float2(ar[r], ai2[r]);
  }
}

// K8: out[t][p][o] = Re sum_{m=-63..63} G[t][m][o] e^{2pi i m p/255}
//  = sum_{m=0..63} C[m][o] cos(2pi m p/255) + S[m][o] sin(...),
//  C[0]=Gr[0],S[0]=0; C[m]=Gr[m]+Gr[-m], S[m]=Gi[-m]-Gi[m].
// grid (t=128, pq=4), block (p64 lanes x og4, 16 o per thread), twiddle by rotation.
__global__ __launch_bounds__(256) void k_idft(const float2* __restrict__ G, const float2* __restrict__ tw,
                                              float* __restrict__ out) {
  int t = blockIdx.x, pq = blockIdx.y;
  int pl = threadIdx.x & 63, og = threadIdx.x >> 6;
  __shared__ __align__(16) unsigned char smem[65536];
  float2 (*CSs)[64] = reinterpret_cast<float2(*)[64]>(smem);
  float (*Ls)[65] = reinterpret_cast<float(*)[65]>(smem);  // aliased after resync
  for (int idx = threadIdx.x; idx < 4096; idx += 256) {
    int m = idx >> 6, oo = idx & 63;
    float2 v;
    if (m == 0) {
      float2 g = G[((size_t)t * 127 + 63) * 64 + oo];
      v = make_float2(g.x, 0.f);
    } else {
      float2 gp = G[((size_t)t * 127 + 63 + m) * 64 + oo];
      float2 gm = G[((size_t)t * 127 + 63 - m) * 64 + oo];
      v = make_float2(gp.x + gm.x, gm.y - gp.y);
    }
    CSs[m][oo] = v;
  }
  __syncthreads();
  int p = pq * 64 + pl;
  float2 wp = tw[p < 255 ? p : 0];
  float twr = 1.f, twi = 0.f;
  float acc[16];
#pragma unroll
  for (int r = 0; r < 16; ++r) acc[r] = 0.f;
  int ob = og * 16;
  for (int m = 0; m < 64; ++m) {
#pragma unroll
    for (int q = 0; q < 8; ++q) {
      float4 cs = *reinterpret_cast<const float4*>(&CSs[m][ob + q * 2]);
      acc[q * 2 + 0] += cs.x * twr + cs.y * twi;
      acc[q * 2 + 1] += cs.z * twr + cs.w * twi;
    }
    float nr = twr * wp.x - twi * wp.y;
    twi = twr * wp.y + twi * wp.x;
    twr = nr;
  }
  __syncthreads();
#pragma unroll
  for (int r = 0; r < 16; ++r) Ls[pl][ob + r] = acc[r];
  __syncthreads();
  for (int idx = threadIdx.x; idx < 4096; idx += 256) {
    int rr = idx >> 6, oo = idx & 63;
    int pg = pq * 64 + rr;
    if (pg < 255) out[((size_t)t * 255 + pg) * 64 + oo] = Ls[rr][oo];
  }
}

extern "C" void kernel_launch(void* const* d_in, const int* in_sizes, int n_in,
                              void* d_out, int out_size, void* d_ws, size_t ws_size,
                              hipStream_t stream) {
  (void)in_sizes; (void)n_in; (void)out_size;
  if (ws_size < WS_FLOATS * sizeof(float)) return;  // ws too small -> visible failure

  const float* x  = (const float*)d_in[0];
  const float* te = (const float*)d_in[1];
  const float* Ar = (const float*)d_in[2];
  const float* Ai = (const float*)d_in[3];
  const float* Rr = (const float*)d_in[4];
  const float* Ri = (const float*)d_in[5];
  float* out = (float*)d_out;

  float* ws = (float*)d_ws;
  float*  P   = ws + OFF_P;
  float*  w   = ws + OFF_W;
  float2* tw  = (float2*)(ws + OFF_TW);
  float2* Fmw = (float2*)(ws + OFF_FMW);
  float2* tc  = (float2*)(ws + OFF_TC);
  float2* flm = (float2*)(ws + OFF_FLM);
  float2* Rt  = (float2*)(ws + OFF_RT);
  float2* fo  = (float2*)(ws + OFF_FO);
  float2* G   = (float2*)(ws + OFF_G);

  k_tables<<<1, 256, 0, stream>>>(w, tw);
  k_legendre<<<64, 128, 0, stream>>>(P);
  k_fwd_dft<<<dim3(128, 2), 256, 0, stream>>>(x, w, tw, Fmw);
  k_tc<<<64 * 127, 256, 0, stream>>>(te, Ar, Ai, tc);
  k_rt<<<dim3(64, 16), 256, 0, stream>>>(Rr, Ri, tc, Rt);
  k_flm<<<dim3(64, 4), 256, 0, stream>>>(P, Fmw, flm);
  k_flmout<<<dim3(64, 8), 256, 0, stream>>>(flm, Rt, fo);
  k_g<<<dim3(127, 2), 256, 0, stream>>>(P, fo, G);
  k_idft<<<dim3(128, 4), 256, 0, stream>>>(G, tw, out);
}

// Round 2
// 422.555 us; speedup vs baseline: 1.1766x; 1.1766x over previous
//
#include <hip/hip_runtime.h>
#include <math.h>

// SphericalSpectralTimeConv: L_in=L_out=128 (NT=128 thetas, NPHI=255 phis),
// Lf=64 (NM=64 m>=0, NJ=127 signed m), Cin=Cout=64, T=256.
//
// ws layout (float offsets). G overlaps FMW/TC/FLM/RT which are dead by the
// time k_g runs. Total = 3,678,720 floats = 14.7 MB.
#define PI_D 3.14159265358979323846
static const size_t OFF_P   = 0;         // float  [64m][64l][128t]
static const size_t OFF_W   = 524288;    // float  [128]
static const size_t OFF_TW  = 524416;    // float2 [255]
static const size_t OFF_FMW = 524928;    // float2 [64m][128t][64c]
static const size_t OFF_TC  = 1573504;   // float2 [64l][127j]
static const size_t OFF_FLM = 1589760;   // float2 [64l][64m][64c]
static const size_t OFF_RT  = 2114048;   // float2 [64l][64o][64i]
static const size_t OFF_FO  = 2638336;   // float2 [64l][127j][64o]
static const size_t OFF_G   = 524928;    // float2 [128t][127j][64o] (overlay)
static const size_t WS_FLOATS = 3678720;

// K0 v2: quadrature weights, parallel: block = theta t (128), thread = m term
// (255 active). Direct double trig per term + LDS tree reduction.
__global__ __launch_bounds__(256) void k_tables(float* __restrict__ w, float2* __restrict__ tw) {
  int t = blockIdx.x;
  int tid = threadIdx.x;
  if (t == 0 && tid < 255) {
    double a = 2.0 * PI_D * tid / 255.0;
    tw[tid] = make_float2((float)cos(a), (float)sin(a));
  }
  double term = 0.0;
  if (tid < 255) {
    int m = tid - 127;
    double br = 0.0, bi = 0.0; bool active = true;
    if (m == 1) bi = PI_D / 2.0;
    else if (m == -1) bi = -PI_D / 2.0;
    else if ((m & 1) == 0) br = 2.0 / (1.0 - (double)m * (double)m);
    else active = false;
    if (active) {
      double md = (double)m;
      double ca = cos(PI_D * md / 255.0), sa = -sin(PI_D * md / 255.0);   // e^{-i pi m/255}
      double wr = br * ca - bi * sa;
      double wi = br * sa + bi * ca;
      double a1 = 2.0 * PI_D * md * t / 255.0;
      double fr = cos(a1), fi = -sin(a1);                                  // e^{-2pi i m t/255}
      if (t < 127) {
        double a2 = 2.0 * PI_D * md * (t + 1) / 255.0;
        fr += cos(a2); fi += sin(a2);                                      // + e^{+2pi i m (t+1)/255}
      }
      term = wr * fr - wi * fi;
    }
  }
  __shared__ double red[256];
  red[tid] = term;
  __syncthreads();
  for (int off = 128; off; off >>= 1) {
    if (tid < off) red[tid] += red[tid + off];
    __syncthreads();
  }
  if (tid == 0) w[t] = (float)(red[0] * 2.0 * PI_D / (255.0 * 255.0));
}

// K1: associated Legendre table P[m][l][t], l,m < 64, t < 128 (double recurrences).
__global__ __launch_bounds__(128) void k_legendre(float* __restrict__ P) {
  int m = blockIdx.x, t = threadIdx.x;
  double th = PI_D * (2 * t + 1) / 255.0;
  double ct = cos(th), st = sin(th);
  double pmm = 0.28209479177387814;  // 1/sqrt(4 pi)
  for (int k = 1; k <= m; ++k) pmm *= -sqrt((2.0 * k + 1.0) / (2.0 * k)) * st;
  float* Pm = P + ((size_t)m * 64) * 128;
  Pm[(size_t)m * 128 + t] = (float)pmm;
  if (m + 1 < 64) {
    double p0 = pmm, p1 = sqrt(2.0 * m + 3.0) * ct * pmm;
    Pm[(size_t)(m + 1) * 128 + t] = (float)p1;
    for (int l = m + 2; l < 64; ++l) {
      double ll = (double)l * l, mm = (double)m * m;
      double a = sqrt((4.0 * ll - 1.0) / (ll - mm));
      double b = sqrt((2.0 * l + 1.0) * ((double)(l - 1) * (l - 1) - mm) / ((2.0 * l - 3.0) * (ll - mm)));
      double pl = a * ct * p1 - b * p0;
      Pm[(size_t)l * 128 + t] = (float)pl;
      p0 = p1; p1 = pl;
    }
  }
}

// K2 v2: forward DFT over phi. Fmw[m][t][c] = w[t] * sum_p x[t][p][c] e^{-2pi i m p/255}.
// grid (t=128, mq=8), block 256 = (c64 lanes x ms4), 2 m per thread, twiddle by
// in-register complex rotation (no LDS gather in the inner loop).
__global__ __launch_bounds__(256) void k_fwd_dft(const float* __restrict__ x, const float* __restrict__ w,
                                                 const float2* __restrict__ tw, float2* __restrict__ Fmw) {
  int t = blockIdx.x, mq = blockIdx.y;
  __shared__ float xs[255 * 64];  // 63.75 KB, x[t] row
  int tid = threadIdx.x;
  for (int idx = tid; idx < 255 * 64; idx += 256) xs[idx] = x[(size_t)t * (255 * 64) + idx];
  __syncthreads();
  int c = tid & 63, ms = tid >> 6;
  int m0 = mq * 8 + ms * 2;
  float2 wm0 = tw[m0], wm1 = tw[m0 + 1];
  float cr0 = wm0.x, ci0 = -wm0.y;  // e^{-2pi i m0/255}
  float cr1 = wm1.x, ci1 = -wm1.y;
  float tr0 = 1.f, ti0 = 0.f, tr1 = 1.f, ti1 = 0.f;
  float a0r = 0.f, a0i = 0.f, a1r = 0.f, a1i = 0.f;
#pragma unroll 5
  for (int p = 0; p < 255; ++p) {
    float xv = xs[p * 64 + c];
    a0r += xv * tr0; a0i += xv * ti0;
    a1r += xv * tr1; a1i += xv * ti1;
    float n0 = tr0 * cr0 - ti0 * ci0; ti0 = tr0 * ci0 + ti0 * cr0; tr0 = n0;
    float n1 = tr1 * cr1 - ti1 * ci1; ti1 = tr1 * ci1 + ti1 * cr1; tr1 = n1;
  }
  float wt = w[t];
  Fmw[((size_t)m0 * 128 + t) * 64 + c] = make_float2(wt * a0r, wt * a0i);
  Fmw[((size_t)(m0 + 1) * 128 + t) * 64 + c] = make_float2(wt * a1r, wt * a1i);
}

// K3: t_c[l][j] = sum_t t_emb[t] * (A_real + i A_imag)[l][j][t]. One block per (l,j).
__global__ __launch_bounds__(256) void k_tc(const float* __restrict__ te, const float* __restrict__ Ar,
                                            const float* __restrict__ Ai, float2* __restrict__ tc) {
  int bid = blockIdx.x;  // l*127 + j
  int tid = threadIdx.x;
  float e = te[tid];
  float vr = Ar[(size_t)bid * 256 + tid] * e;
  float vi = Ai[(size_t)bid * 256 + tid] * e;
  for (int off = 32; off; off >>= 1) {
    vr += __shfl_down(vr, off);
    vi += __shfl_down(vi, off);
  }
  __shared__ float2 red[4];
  if ((tid & 63) == 0) red[tid >> 6] = make_float2(vr, vi);
  __syncthreads();
  if (tid == 0) {
    float2 s = red[0];
    for (int q = 1; q < 4; ++q) { s.x += red[q].x; s.y += red[q].y; }
    tc[bid] = s;
  }
}

// K4 v2: Rt[l][o][i] = sum_j t_c[l][j] * (R_real + i R_imag)[l][j][o][i].
// HBM-bound (266 MB). float4 loads, tc staged in LDS (off the vmcnt queue),
// grid (64 l, 4 og), block 256 = (ic16 x o16), unroll 4 -> ~8KB in flight/wave.
__global__ __launch_bounds__(256) void k_rt(const float* __restrict__ Rr, const float* __restrict__ Ri,
                                            const float2* __restrict__ tc, float2* __restrict__ Rt) {
  int l = blockIdx.x, og = blockIdx.y;
  int tid = threadIdx.x;
  __shared__ float2 tcs[127];
  if (tid < 127) tcs[tid] = tc[l * 127 + tid];
  __syncthreads();
  int ic = tid & 15, ol = tid >> 4;
  int o = og * 16 + ol;
  const float* rr = Rr + ((size_t)l * 127) * 4096 + o * 64 + ic * 4;
  const float* ri = Ri + ((size_t)l * 127) * 4096 + o * 64 + ic * 4;
  float4 ar = make_float4(0.f, 0.f, 0.f, 0.f);
  float4 ai = make_float4(0.f, 0.f, 0.f, 0.f);
#pragma unroll 4
  for (int j = 0; j < 127; ++j) {
    float2 w2 = tcs[j];
    float4 a = *reinterpret_cast<const float4*>(rr + (size_t)j * 4096);
    float4 b = *reinterpret_cast<const float4*>(ri + (size_t)j * 4096);
    ar.x += w2.x * a.x - w2.y * b.x;  ai.x += w2.x * b.x + w2.y * a.x;
    ar.y += w2.x * a.y - w2.y * b.y;  ai.y += w2.x * b.y + w2.y * a.y;
    ar.z += w2.x * a.z - w2.y * b.z;  ai.z += w2.x * b.z + w2.y * a.z;
    ar.w += w2.x * a.w - w2.y * b.w;  ai.w += w2.x * b.w + w2.y * a.w;
  }
  float4* rt4 = reinterpret_cast<float4*>(Rt);
  size_t base = ((size_t)l * 64 + o) * 32 + ic * 2;   // float4 units (2 complex each)
  rt4[base]     = make_float4(ar.x, ai.x, ar.y, ai.y);
  rt4[base + 1] = make_float4(ar.z, ai.z, ar.w, ai.w);
}

// K5 v2: flm[l][m][c] = sum_t P[m][l][t] * Fmw[m][t][c].
// grid (m=64, lq=8), block (c64 x lg4), 2 l per thread, P staged in LDS,
// 32-t quarters -> 33 KB LDS, 2 blocks/CU.
__global__ __launch_bounds__(256) void k_flm(const float* __restrict__ P, const float2* __restrict__ Fmw,
                                             float2* __restrict__ flm) {
  int m = blockIdx.x, lq = blockIdx.y;
  int tid = threadIdx.x;
  int c = tid & 63, lg = tid >> 6;
  __shared__ float2 Fs[32][64];  // 32 KB
  __shared__ float Ps[8][32];    // 1 KB
  float2 acc[2];
  acc[0] = make_float2(0.f, 0.f);
  acc[1] = make_float2(0.f, 0.f);
  for (int q = 0; q < 4; ++q) {
    __syncthreads();
    for (int idx = tid; idx < 2048; idx += 256) {
      int tt = idx >> 6, cc = idx & 63;
      Fs[tt][cc] = Fmw[((size_t)m * 128 + q * 32 + tt) * 64 + cc];
    }
    {
      int ll = tid >> 5, tt2 = tid & 31;
      int l = m + lq * 8 + ll;
      Ps[ll][tt2] = (l < 64) ? P[((size_t)m * 64 + l) * 128 + q * 32 + tt2] : 0.f;
    }
    __syncthreads();
    int li = lg * 2;
#pragma unroll 8
    for (int tt = 0; tt < 32; ++tt) {
      float2 f = Fs[tt][c];
      float p0 = Ps[li][tt], p1 = Ps[li + 1][tt];
      acc[0].x += p0 * f.x; acc[0].y += p0 * f.y;
      acc[1].x += p1 * f.x; acc[1].y += p1 * f.y;
    }
  }
#pragma unroll
  for (int s = 0; s < 2; ++s) {
    int l = m + lq * 8 + lg * 2 + s;
    if (l < 64) flm[((size_t)l * 64 + m) * 64 + c] = acc[s];
  }
}

// K6: flm_out[l][j][o] = sum_i flm_signed[l][j][i] * Rt[l][o][i] (complex*complex).
__global__ __launch_bounds__(256) void k_flmout(const float2* __restrict__ flm, const float2* __restrict__ Rt,
                                                float2* __restrict__ fo) {
  int l = blockIdx.x, jg = blockIdx.y;
  int o = threadIdx.x & 63, js = threadIdx.x >> 6;
  __shared__ float2 Rts[64][65];
  __shared__ float2 Fjs[16][64];
  for (int idx = threadIdx.x; idx < 4096; idx += 256) {
    int oo = idx >> 6, ii = idx & 63;
    Rts[oo][ii] = Rt[((size_t)l * 64 + oo) * 64 + ii];
  }
  for (int idx = threadIdx.x; idx < 1024; idx += 256) {
    int jl = idx >> 6, ii = idx & 63;
    int j = jg * 16 + jl;
    float2 v = make_float2(0.f, 0.f);
    if (j < 127) {
      int mm = j - 63, am = mm < 0 ? -mm : mm;
      if (l >= am) {
        float2 f = flm[((size_t)l * 64 + am) * 64 + ii];
        if (mm < 0) { float s = (am & 1) ? -1.f : 1.f; v = make_float2(s * f.x, -s * f.y); }
        else v = f;
      }
    }
    Fjs[jl][ii] = v;
  }
  __syncthreads();
  float2 acc[4];
#pragma unroll
  for (int q = 0; q < 4; ++q) acc[q] = make_float2(0.f, 0.f);
  for (int i = 0; i < 64; ++i) {
    float2 r = Rts[o][i];
#pragma unroll
    for (int q = 0; q < 4; ++q) {
      float2 f = Fjs[js * 4 + q][i];
      acc[q].x += f.x * r.x - f.y * r.y;
      acc[q].y += f.x * r.y + f.y * r.x;
    }
  }
#pragma unroll
  for (int q = 0; q < 4; ++q) {
    int j = jg * 16 + js * 4 + q;
    if (j < 127) fo[((size_t)l * 127 + j) * 64 + o] = acc[q];
  }
}

// K7: G[t][j][o] = sgn * sum_{l>=|m|} P[|m|][l][t] * flm_out[l][j][o].
__global__ __launch_bounds__(256) void k_g(const float* __restrict__ P, const float2* __restrict__ fo,
                                           float2* __restrict__ G) {
  int j = blockIdx.x, tg = blockIdx.y;
  int mm = j - 63, am = mm < 0 ? -mm : mm;
  float sgn = (mm < 0 && (am & 1)) ? -1.f : 1.f;
  int o = threadIdx.x & 63, ts = threadIdx.x >> 6;
  __shared__ float Ps[64][64];
  __shared__ float2 Fos[64][64];
  for (int idx = threadIdx.x; idx < 4096; idx += 256) {
    int ll = idx >> 6, tt = idx & 63;
    Ps[ll][tt] = P[((size_t)am * 64 + ll) * 128 + tg * 64 + tt];
  }
  for (int idx = threadIdx.x; idx < 4096; idx += 256) {
    int ll = idx >> 6, oo = idx & 63;
    float2 v = fo[((size_t)ll * 127 + j) * 64 + oo];
    Fos[ll][oo] = make_float2(sgn * v.x, sgn * v.y);
  }
  __syncthreads();
  float ar[16], ai2[16];
#pragma unroll
  for (int r = 0; r < 16; ++r) { ar[r] = 0.f; ai2[r] = 0.f; }
  for (int l = am; l < 64; ++l) {
    float2 f = Fos[l][o];
#pragma unroll
    for (int q = 0; q < 4; ++q) {
      float4 pv = *reinterpret_cast<const float4*>(&Ps[l][ts * 16 + q * 4]);
      ar[q * 4 + 0] += pv.x * f.x;  ai2[q * 4 + 0] += pv.x * f.y;
      ar[q * 4 + 1] += pv.y * f.x;  ai2[q * 4 + 1] += pv.y * f.y;
      ar[q * 4 + 2] += pv.z * f.x;  ai2[q * 4 + 2] += pv.z * f.y;
      ar[q * 4 + 3] += pv.w * f.x;  ai2[q * 4 + 3] += pv.w * f.y;
    }
  }
#pragma unroll
  for (int r = 0; r < 16; ++r) {
    int t = tg * 64 + ts * 16 + r;
    G[((size_t)t * 127 + j) * 64 + o] = make_float2(ar[r], ai2[r]);
  }
}

// K8: out[t][p][o] = Re sum_m G[t][m][o] e^{2pi i m p/255} via cos/sin split.
__global__ __launch_bounds__(256) void k_idft(const float2* __restrict__ G, const float2* __restrict__ tw,
                                              float* __restrict__ out) {
  int t = blockIdx.x, pq = blockIdx.y;
  int pl = threadIdx.x & 63, og = threadIdx.x >> 6;
  __shared__ __align__(16) unsigned char smem[65536];
  float2 (*CSs)[64] = reinterpret_cast<float2(*)[64]>(smem);
  float (*Ls)[65] = reinterpret_cast<float(*)[65]>(smem);  // aliased after resync
  for (int idx = threadIdx.x; idx < 4096; idx += 256) {
    int m = idx >> 6, oo = idx & 63;
    float2 v;
    if (m == 0) {
      float2 g = G[((size_t)t * 127 + 63) * 64 + oo];
      v = make_float2(g.x, 0.f);
    } else {
      float2 gp = G[((size_t)t * 127 + 63 + m) * 64 + oo];
      float2 gm = G[((size_t)t * 127 + 63 - m) * 64 + oo];
      v = make_float2(gp.x + gm.x, gm.y - gp.y);
    }
    CSs[m][oo] = v;
  }
  __syncthreads();
  int p = pq * 64 + pl;
  float2 wp = tw[p < 255 ? p : 0];
  float twr = 1.f, twi = 0.f;
  float acc[16];
#pragma unroll
  for (int r = 0; r < 16; ++r) acc[r] = 0.f;
  int ob = og * 16;
  for (int m = 0; m < 64; ++m) {
#pragma unroll
    for (int q = 0; q < 8; ++q) {
      float4 cs = *reinterpret_cast<const float4*>(&CSs[m][ob + q * 2]);
      acc[q * 2 + 0] += cs.x * twr + cs.y * twi;
      acc[q * 2 + 1] += cs.z * twr + cs.w * twi;
    }
    float nr = twr * wp.x - twi * wp.y;
    twi = twr * wp.y + twi * wp.x;
    twr = nr;
  }
  __syncthreads();
#pragma unroll
  for (int r = 0; r < 16; ++r) Ls[pl][ob + r] = acc[r];
  __syncthreads();
  for (int idx = threadIdx.x; idx < 4096; idx += 256) {
    int rr = idx >> 6, oo = idx & 63;
    int pg = pq * 64 + rr;
    if (pg < 255) out[((size_t)t * 255 + pg) * 64 + oo] = Ls[rr][oo];
  }
}

extern "C" void kernel_launch(void* const* d_in, const int* in_sizes, int n_in,
                              void* d_out, int out_size, void* d_ws, size_t ws_size,
                              hipStream_t stream) {
  (void)in_sizes; (void)n_in; (void)out_size;
  if (ws_size < WS_FLOATS * sizeof(float)) return;  // ws too small -> visible failure

  const float* x  = (const float*)d_in[0];
  const float* te = (const float*)d_in[1];
  const float* Ar = (const float*)d_in[2];
  const float* Ai = (const float*)d_in[3];
  const float* Rr = (const float*)d_in[4];
  const float* Ri = (const float*)d_in[5];
  float* out = (float*)d_out;

  float* ws = (float*)d_ws;
  float*  P   = ws + OFF_P;
  float*  w   = ws + OFF_W;
  float2* tw  = (float2*)(ws + OFF_TW);
  float2* Fmw = (float2*)(ws + OFF_FMW);
  float2* tc  = (float2*)(ws + OFF_TC);
  float2* flm = (float2*)(ws + OFF_FLM);
  float2* Rt  = (float2*)(ws + OFF_RT);
  float2* fo  = (float2*)(ws + OFF_FO);
  float2* G   = (float2*)(ws + OFF_G);

  k_tables<<<128, 256, 0, stream>>>(w, tw);
  k_legendre<<<64, 128, 0, stream>>>(P);
  k_fwd_dft<<<dim3(128, 8), 256, 0, stream>>>(x, w, tw, Fmw);
  k_tc<<<64 * 127, 256, 0, stream>>>(te, Ar, Ai, tc);
  k_rt<<<dim3(64, 4), 256, 0, stream>>>(Rr, Ri, tc, Rt);
  k_flm<<<dim3(64, 8), 256, 0, stream>>>(P, Fmw, flm);
  k_flmout<<<dim3(64, 8), 256, 0, stream>>>(flm, Rt, fo);
  k_g<<<dim3(127, 2), 256, 0, stream>>>(P, fo, G);
  k_idft<<<dim3(128, 4), 256, 0, stream>>>(G, tw, out);
}